// Round 10
// baseline (73.636 us; speedup 1.0000x reference)
//
#include <hip/hip_runtime.h>

// Quantum circuit sim — radix-16, layer 0 folded into a product-state init
// (R12, verified absmax=0), layer-1 RZs factored into per-pass 4-wire slot
// diagonals + per-thread e_t (wires 12,13). CNOT chain folded into
// store-address XORs with the prefix-xor perm D(o); wires 12,13 via
// quad_perm DPP inside p=2; final layer RZ-free by |.|^2 invariance;
// measurement + head fused in registers. 1024 threads, 16 amps/thread.
// 6 template-specialized sweeps (R18), 3 barriers + 2 fences (R17).
//
// R22 — REVERT to R19 (verified 72.94us, absmax 0.0). The R20/R21 layer-2
// pass reorder (p1,p2,p0 — would convert 1 more barrier to a fence,
// ~0.7us) failed twice with deterministic absmax 0.295/0.356 under two
// different carry hypotheses; per-piece re-audit (carries, wave-closure
// cosets, MEAS2 prefix table, coefLow map) all check out individually, so
// the bug is an interaction not isolatable without a local reference sim.
// Branch CLOSED: do not retry blindly. Remaining kernel headroom < 1.5%
// of dur_us; every other lever refuted (R15 ILP swap null; pk-math
// half-rate on gfx950; additive-pad layouts bank-conflict on p=2).
//
// Structural accounting (slug-calibrated R14): dur 72.94 = harness floor
// ~53.8us (39.4 fill + ~14.4 reset dispatches) + kernel K ~19us.
// K = VALU ~9.5us (3-shear op floor; issue model instrs x 2cyc x
// 4waves/SIMD validated R16/R18/R19) + DS ~6us (BW-minimal b64) +
// ~3.5us barrier/convoy (2 provably-safe boundaries already fences).
//
// R19: 3-shear RY register gates: a1 = a - tau*d; d' = d + s*a1;
// a' = a1 - tau*d', tau = tan(theta/2) = s/(1+c) packed in gtr.w. Exact.
// R18: sweep<L,P> if-constexpr — masks/indices literal.
// R17: p1->p2 boundaries wave-closed (store slot-set == read slot-set
// per wave = swz({A[13:10]=w}); per-wave in-order DS) -> compiler fence.
// R16: VGPR-resident constants, hoisted zph4 loads, pair-ordered reads.
//
// Perf ledger: base 78.35 -> R16 77.59 -> R17 76.88 -> R18 74.84 ->
// R19 72.94 -> R20/R21 FAIL (reorder) -> R22 revert to R19.
//
// LDS swizzle slot = i ^ ((i>>4)&15) ^ ((i>>8)&15) ^ ((i>>9)&16), GF2-linear.
// No indexable per-thread arrays (FETCH_SIZE = spill canary).

#define NW      14
#define NSTATE  (1 << NW)
#define TPB     1024
#define NLAYERS 3

typedef float v2f __attribute__((ext_vector_type(2)));

__device__ constexpr int swz(int i) {
    return i ^ ((i >> 4) & 15) ^ ((i >> 8) & 15) ^ ((i >> 9) & 16);
}
__device__ __forceinline__ v2f vswp(v2f a) { return __builtin_shufflevector(a, a, 1, 0); }
__device__ __forceinline__ v2f vspl(float x) { v2f r; r.x = x;  r.y = x; return r; }
__device__ __forceinline__ v2f vpm(float x)  { v2f r; r.x = -x; r.y = x; return r; }
// complex multiply (a.x+i a.y)(b.x+i b.y)
__device__ __forceinline__ v2f cml(v2f a, v2f b) {
    return vspl(a.x) * b + vpm(a.y) * vswp(b);
}
template <int CTRL>
__device__ __forceinline__ v2f dpp2(v2f a) {
    v2f r;
    r.x = __int_as_float(__builtin_amdgcn_update_dpp(
              0, __float_as_int(a.x), CTRL, 0xF, 0xF, true));
    r.y = __int_as_float(__builtin_amdgcn_update_dpp(
              0, __float_as_int(a.y), CTRL, 0xF, 0xF, true));
    return r;
}
// R19: 3-shear real rotation on (a,d): tau = tan(theta/2), s = sin(theta)
// a1 = a - tau*d; d' = d + s*a1; a' = a1 - tau*d'  (exact; 6 FMA-class ops)
__device__ __forceinline__ void pgr_sh(v2f& a, v2f& d, float tau, float s) {
    const v2f a1 = a - vspl(tau) * d;
    d = d + vspl(s) * a1;
    a = a1 - vspl(tau) * d;
}

// gtr packs {c, -s, s, tau}; PGR4 consumes (tau, s)
#define PGR4(a, d, pre) pgr_sh(a, d, pre.w, pre.z)

// 4-wire diagonal: one float4 = phases for slots (2k, 2k+1), pre-hoisted
#define PH2(aE, aO, Z_) { \
    aE = vspl(Z_.x)*aE + vpm(Z_.y)*vswp(aE); \
    aO = vspl(Z_.z)*aO + vpm(Z_.w)*vswp(aO); }

// real DPP lane gate (direct form: shear would need 3 DPP fetches)
#define LGR1(aX, CT) { const v2f p_ = dpp2<CT>(aX); \
    aX = vspl(cor)*aX + vspl(cpr)*p_; }
#define LGR_ALL(CT) \
    LGR1(a0,CT) LGR1(a1,CT) LGR1(a2,CT) LGR1(a3,CT) \
    LGR1(a4,CT) LGR1(a5,CT) LGR1(a6,CT) LGR1(a7,CT) \
    LGR1(a8,CT) LGR1(a9,CT) LGR1(aA,CT) LGR1(aB,CT) \
    LGR1(aC,CT) LGR1(aD,CT) LGR1(aE,CT) LGR1(aF,CT)

// per-thread wires-12/13 phase
#define ETA(aX) { aX = vspl(et.x)*aX + vpm(et.y)*vswp(aX); }
#define ETA_ALL \
    ETA(a0) ETA(a1) ETA(a2) ETA(a3) ETA(a4) ETA(a5) ETA(a6) ETA(a7) \
    ETA(a8) ETA(a9) ETA(aA) ETA(aB) ETA(aC) ETA(aD) ETA(aE) ETA(aF)

// measurement: Dn = dest nibble (cs=0), par = parity(o)
#define MEAS(aX, Dn, par) { \
    const float m_ = ((Dn)&8?-h8:h8)+((Dn)&4?-h9:h9)+((Dn)&2?-h10:h10)+((Dn)&1?-h11:h11); \
    const float cf_ = coefHigh + sc*m_ + ((par)? -Wp : Wp); \
    acc += (aX.x*aX.x + aX.y*aX.y)*cf_; }

// ---- one sweep, fully specialized at compile time ----
template <int L, int P>
__device__ __forceinline__ void sweep(
    v2f* __restrict__ psi, const float4* __restrict__ gtr,
    const float4* __restrict__ zph4, const v2f* __restrict__ zph12,
    const v2f (* __restrict__ vws)[2], const float* __restrict__ hws,
    const int t, float& acc)
{
    constexpr int SB = 10 - 4 * P;
    constexpr int LO = 1 << SB;
    constexpr int S0 = swz(LO),      S1 = swz(LO << 1);
    constexpr int S2 = swz(LO << 2), S3 = swz(LO << 3);
    constexpr int M  = S3 ^ S2 ^ S1 ^ S0;
    constexpr int zb = P * 8;
    constexpr int gl = (L - 1) * NW;

    // gate constants: immediate-indexed LDS loads, VGPR-resident (R16)
    const float4 ga = gtr[gl + 4 * P + 0];
    const float4 gb = gtr[gl + 4 * P + 1];
    const float4 gc = gtr[gl + 4 * P + 2];
    const float4 gd = gtr[gl + 4 * P + 3];

    const int i0 = ((t >> SB) << (SB + 4)) | (t & (LO - 1));
    const int s  = swz(i0);

    v2f a0, a1, a2, a3, a4, a5, a6, a7;
    v2f a8, a9, aA, aB, aC, aD, aE, aF;
    float4 Z0, Z1, Z2, Z3, Z4, Z5, Z6, Z7;   // PH2 phases (L==1)

    if constexpr (L == 1 && P == 0) {
        // ---- post-layer-0 product state, chain perm folded ----
        v2f base = cml(vws[5][((t >> 8) ^ (t >> 9)) & 1],
                       vws[6][((t >> 7) ^ (t >> 8)) & 1]);
        v2f m2   = cml(vws[7][((t >> 6) ^ (t >> 7)) & 1],
                       vws[8][((t >> 5) ^ (t >> 6)) & 1]);
        v2f m3   = cml(vws[9][((t >> 4) ^ (t >> 5)) & 1],
                       vws[10][((t >> 3) ^ (t >> 4)) & 1]);
        v2f m4   = cml(vws[11][((t >> 2) ^ (t >> 3)) & 1],
                       vws[12][((t >> 1) ^ (t >> 2)) & 1]);
        base = cml(base, m2);
        m3   = cml(m3, m4);
        base = cml(base, m3);
        base = cml(base, vws[13][(t ^ (t >> 1)) & 1]);
        const int t9 = (t >> 9) & 1;
        const v2f B0 = cml(base, vws[4][t9]);
        const v2f B1 = cml(base, vws[4][t9 ^ 1]);
        const v2f w3B00 = cml(vws[3][0], B0);
        const v2f w3B01 = cml(vws[3][1], B1);
        const v2f w3B10 = cml(vws[3][1], B0);
        const v2f w3B11 = cml(vws[3][0], B1);
        v2f p_, t20, t21;
        p_ = cml(vws[0][0], vws[1][0]);
        t20 = cml(p_, vws[2][0]); t21 = cml(p_, vws[2][1]);
        a0 = cml(t20, w3B00); a1 = cml(t20, w3B01);
        a2 = cml(t21, w3B10); a3 = cml(t21, w3B11);
        p_ = cml(vws[0][0], vws[1][1]);
        t20 = cml(p_, vws[2][1]); t21 = cml(p_, vws[2][0]);
        a4 = cml(t20, w3B00); a5 = cml(t20, w3B01);
        a6 = cml(t21, w3B10); a7 = cml(t21, w3B11);
        p_ = cml(vws[0][1], vws[1][1]);
        t20 = cml(p_, vws[2][0]); t21 = cml(p_, vws[2][1]);
        a8 = cml(t20, w3B00); a9 = cml(t20, w3B01);
        aA = cml(t21, w3B10); aB = cml(t21, w3B11);
        p_ = cml(vws[0][1], vws[1][0]);
        t20 = cml(p_, vws[2][1]); t21 = cml(p_, vws[2][0]);
        aC = cml(t20, w3B00); aD = cml(t20, w3B01);
        aE = cml(t21, w3B10); aF = cml(t21, w3B11);
        Z0 = zph4[zb + 0]; Z1 = zph4[zb + 1];
        Z2 = zph4[zb + 2]; Z3 = zph4[zb + 3];
        Z4 = zph4[zb + 4]; Z5 = zph4[zb + 5];
        Z6 = zph4[zb + 6]; Z7 = zph4[zb + 7];
    } else {
        // pair-ordered reads: first PGR4 (a0,a8) needs only the first 2
        // in-order DS returns -> early compute start. Masks are literals.
        a0 = psi[s];                a8 = psi[s ^ S3];
        a1 = psi[s ^ S0];           a9 = psi[s ^ S3 ^ S0];
        a2 = psi[s ^ S1];           aA = psi[s ^ S3 ^ S1];
        a3 = psi[s ^ S1 ^ S0];      aB = psi[s ^ S3 ^ S1 ^ S0];
        a4 = psi[s ^ S2];           aC = psi[s ^ S3 ^ S2];
        a5 = psi[s ^ S2 ^ S0];      aD = psi[s ^ S3 ^ S2 ^ S0];
        a6 = psi[s ^ S2 ^ S1];      aE = psi[s ^ S3 ^ S2 ^ S1];
        a7 = psi[s ^ S2 ^ S1 ^ S0]; aF = psi[s ^ M];
        if constexpr (L == 1) {
            // issue after amp reads: latency hides under the PGR4s
            Z0 = zph4[zb + 0]; Z1 = zph4[zb + 1];
            Z2 = zph4[zb + 2]; Z3 = zph4[zb + 3];
            Z4 = zph4[zb + 4]; Z5 = zph4[zb + 5];
            Z6 = zph4[zb + 6]; Z7 = zph4[zb + 7];
        }
    }

    // 4 real RY gates (bits b3..b0), 3-shear form (R19)
    PGR4(a0, a8, ga); PGR4(a1, a9, ga); PGR4(a2, aA, ga); PGR4(a3, aB, ga);
    PGR4(a4, aC, ga); PGR4(a5, aD, ga); PGR4(a6, aE, ga); PGR4(a7, aF, ga);
    PGR4(a0, a4, gb); PGR4(a1, a5, gb); PGR4(a2, a6, gb); PGR4(a3, a7, gb);
    PGR4(a8, aC, gb); PGR4(a9, aD, gb); PGR4(aA, aE, gb); PGR4(aB, aF, gb);
    PGR4(a0, a2, gc); PGR4(a1, a3, gc); PGR4(a4, a6, gc); PGR4(a5, a7, gc);
    PGR4(a8, aA, gc); PGR4(a9, aB, gc); PGR4(aC, aE, gc); PGR4(aD, aF, gc);
    PGR4(a0, a1, gd); PGR4(a2, a3, gd); PGR4(a4, a5, gd); PGR4(a6, a7, gd);
    PGR4(a8, a9, gd); PGR4(aA, aB, gd); PGR4(aC, aD, gd); PGR4(aE, aF, gd);

    if constexpr (L == 1) {
        // 4-wire RZ diagonal (slot constants, pre-hoisted to VGPRs)
        PH2(a0, a1, Z0) PH2(a2, a3, Z1) PH2(a4, a5, Z2) PH2(a6, a7, Z3)
        PH2(a8, a9, Z4) PH2(aA, aB, Z5) PH2(aC, aD, Z6) PH2(aE, aF, Z7)
    }

    if constexpr (P < 2) {
        const bool cs = ((t >> SB) & 1) != 0;
        const int e = s ^ (cs ? M : 0);
        psi[e]                = a0; psi[e ^ S0]           = a1;
        psi[e ^ S1 ^ S0]      = a2; psi[e ^ S1]           = a3;
        psi[e ^ S2 ^ S1 ^ S0] = a4; psi[e ^ S2 ^ S1]      = a5;
        psi[e ^ S2]           = a6; psi[e ^ S2 ^ S0]      = a7;
        psi[e ^ M]            = a8; psi[e ^ S3 ^ S2 ^ S1] = a9;
        psi[e ^ S3 ^ S2]      = aA; psi[e ^ S3 ^ S2 ^ S0] = aB;
        psi[e ^ S3]           = aC; psi[e ^ S3 ^ S0]      = aD;
        psi[e ^ S3 ^ S1 ^ S0] = aE; psi[e ^ S3 ^ S1]      = aF;
        if constexpr (P == 0) {
            __syncthreads();            // p0->p1 exchange is inter-wave
        } else {
            // p1->p2 exchange is wave-closed (R17 proof): per-wave in-order
            // DS makes own stores visible to own later reads; compiler-only
            // fence stops hoisting of may-alias LDS reads above stores.
            asm volatile("" ::: "memory");
        }
    } else if constexpr (L < NLAYERS - 1) {
        // real lane gates wires 12 (0x4E), 13 (0xB1) + e_t phase
        const float4 gu = gtr[gl + 12];
        const float4 gv = gtr[gl + 13];
        {
            const float cor = gu.x;
            const float cpr = (t & 2) ? gu.z : gu.y;
            LGR_ALL(0x4E)
        }
        {
            const float cor = gv.x;
            const float cpr = (t & 1) ? gv.z : gv.y;
            LGR_ALL(0xB1)
        }
        { const v2f et = zph12[t & 3]; ETA_ALL }
        // extended store: chain through bits 1,0
        const bool cs = ((t >> SB) & 1) != 0;
        const int e = s ^ (cs ? (M ^ 3) : 0) ^ ((t >> 1) & 1);
        psi[e]                    = a0; psi[e ^ S0 ^ 3]           = a1;
        psi[e ^ S1 ^ S0 ^ 3]      = a2; psi[e ^ S1]               = a3;
        psi[e ^ S2 ^ S1 ^ S0 ^ 3] = a4; psi[e ^ S2 ^ S1]          = a5;
        psi[e ^ S2]               = a6; psi[e ^ S2 ^ S0 ^ 3]      = a7;
        psi[e ^ M ^ 3]            = a8; psi[e ^ S3 ^ S2 ^ S1]     = a9;
        psi[e ^ S3 ^ S2]          = aA; psi[e ^ S3 ^ S2 ^ S0 ^ 3] = aB;
        psi[e ^ S3]               = aC; psi[e ^ S3 ^ S0 ^ 3]      = aD;
        psi[e ^ S3 ^ S1 ^ S0 ^ 3] = aE; psi[e ^ S3 ^ S1]          = aF;
        __syncthreads();                // layer crossing is inter-wave
    } else {
        // final layer p=2: real lane gates + fused measurement
        const float4 gu = gtr[gl + 12];
        const float4 gv = gtr[gl + 13];
        {
            const float cor = gu.x;
            const float cpr = (t & 2) ? gu.z : gu.y;
            LGR_ALL(0x4E)
        }
        {
            const float cor = gv.x;
            const float cpr = (t & 1) ? gv.z : gv.y;
            LGR_ALL(0xB1)
        }
        const float h8 = hws[8], h9 = hws[9], h10 = hws[10], h11 = hws[11];
        const float h12 = hws[12], h13 = hws[13];
        float coefHigh = 0.f;           // wires 0..7 from t bits 9..2
#pragma unroll
        for (int j = 0; j < 8; ++j)
            coefHigh += ((t >> (9 - j)) & 1) ? -hws[j] : hws[j];
        const bool cs = ((t >> SB) & 1) != 0;
        const float sc = cs ? -1.f : 1.f;
        const float w12_0 = (t & 2) ? -h12 : h12;
        const float w13_0 = (((t >> 1) ^ t) & 1) ? -h13 : h13;
        const float Ssum = w12_0 + w13_0;
        const float Wp = cs ? -Ssum : Ssum;
        MEAS(a0, 0, 0)  MEAS(a1, 1, 1)  MEAS(a2, 3, 1)  MEAS(a3, 2, 0)
        MEAS(a4, 7, 1)  MEAS(a5, 6, 0)  MEAS(a6, 4, 0)  MEAS(a7, 5, 1)
        MEAS(a8, 15, 1) MEAS(a9, 14, 0) MEAS(aA, 12, 0) MEAS(aB, 13, 1)
        MEAS(aC, 8, 0)  MEAS(aD, 9, 1)  MEAS(aE, 11, 1) MEAS(aF, 10, 0)
    }
}

__global__ void __launch_bounds__(TPB)
qsim_kernel(const float* __restrict__ state_batch,   // [B, NW]
            const float* __restrict__ var_params,    // [NLAYERS, NW, 3]
            const float* __restrict__ head_w,        // [NW]
            const float* __restrict__ head_b,        // [1]
            float* __restrict__ out)                 // [B]
{
    __shared__ v2f    psi[NSTATE];          // 128 KiB
    __shared__ float4 gtr[2 * NW];          // RY gates {c,-s,s,tau}, layers 1,2
    __shared__ float4 zph4[3 * 8];          // L1 per-pass 4-wire diag (16 slots)
    __shared__ v2f    zph12[4];             // L1 wires 12,13 diag by t&3
    __shared__ v2f    vws[NW][2];           // layer-0 product columns
    __shared__ float  hws[NW];
    __shared__ float  red[TPB / 64];

    const int t    = threadIdx.x;
    const int lane = t & 63;
    const int wave = t >> 6;
    const int b    = blockIdx.x;

    // ---- staging ----
    if (t < NW) {
        float sx, cx, sy, cy, sz, cz;
        sincosf(0.5f * state_batch[b * NW + t], &sx, &cx);
        sincosf(0.5f * var_params[t * 3 + 0], &sy, &cy);        // L0 RY
        sincosf(0.5f * var_params[t * 3 + 1], &sz, &cz);        // L0 RZ
        const float tr = cy * cx, ti = sy * sx;
        const float br = sy * cx, bi = -cy * sx;
        v2f v0, v1;
        v0.x = cz * tr + sz * ti;  v0.y = cz * ti - sz * tr;
        v1.x = cz * br - sz * bi;  v1.y = cz * bi + sz * br;
        vws[t][0] = v0; vws[t][1] = v1;
    }
    if (t >= 64 && t < 64 + 2 * NW) {       // RY gates for layers 1,2
        const int g = t - 64;               // g = (l-1)*NW + w
        float sa, ca;
        sincosf(0.5f * var_params[(NW + g) * 3 + 0], &sa, &ca);
        const float tau = sa / (1.f + ca);  // tan(alpha/4)
        gtr[g] = make_float4(ca, -sa, sa, tau);
    }
    if (t >= 128 && t < 128 + NW) hws[t - 128] = head_w[t - 128];
    if (t >= 192 && t < 240) {              // L1 per-pass 4-wire diagonals
        const int k = t - 192, p = k >> 4, o = k & 15;
        float ang = 0.f;
#pragma unroll
        for (int j = 0; j < 4; ++j) {       // o bit (3-j) <-> wire 4p+j
            const float z = var_params[(NW + 4 * p + j) * 3 + 1];
            ang += ((o >> (3 - j)) & 1) ? 0.5f * z : -0.5f * z;
        }
        float s_, c_; sincosf(ang, &s_, &c_);
        if (o & 1) { zph4[p * 8 + (o >> 1)].z = c_; zph4[p * 8 + (o >> 1)].w = s_; }
        else       { zph4[p * 8 + (o >> 1)].x = c_; zph4[p * 8 + (o >> 1)].y = s_; }
    }
    if (t >= 240 && t < 244) {              // L1 wires 12,13 diag by t&3
        const int k2 = t - 240;
        const float z12 = var_params[(NW + 12) * 3 + 1];
        const float z13 = var_params[(NW + 13) * 3 + 1];
        const float ang = ((k2 & 2) ? 0.5f * z12 : -0.5f * z12)
                        + ((k2 & 1) ? 0.5f * z13 : -0.5f * z13);
        float s_, c_; sincosf(ang, &s_, &c_);
        v2f e; e.x = c_; e.y = s_;
        zph12[k2] = e;
    }
    __syncthreads();

    float acc = 0.f;

    // 6 fully-specialized sweeps (R18): masks/indices are literals
    sweep<1, 0>(psi, gtr, zph4, zph12, vws, hws, t, acc);
    sweep<1, 1>(psi, gtr, zph4, zph12, vws, hws, t, acc);
    sweep<1, 2>(psi, gtr, zph4, zph12, vws, hws, t, acc);
    sweep<2, 0>(psi, gtr, zph4, zph12, vws, hws, t, acc);
    sweep<2, 1>(psi, gtr, zph4, zph12, vws, hws, t, acc);
    sweep<2, 2>(psi, gtr, zph4, zph12, vws, hws, t, acc);

    // ---- block reduction + head ----
#pragma unroll
    for (int off = 32; off > 0; off >>= 1)
        acc += __shfl_down(acc, off, 64);
    if (lane == 0) red[wave] = acc;
    __syncthreads();
    if (t == 0) {
        float s = 0.f;
#pragma unroll
        for (int i = 0; i < TPB / 64; ++i) s += red[i];
        out[b] = s + head_b[0];
    }
}

extern "C" void kernel_launch(void* const* d_in, const int* in_sizes, int n_in,
                              void* d_out, int out_size, void* d_ws, size_t ws_size,
                              hipStream_t stream) {
    const float* state_batch = (const float*)d_in[0];
    const float* var_params  = (const float*)d_in[1];
    const float* head_w      = (const float*)d_in[2];
    const float* head_b      = (const float*)d_in[3];
    float* out = (float*)d_out;
    qsim_kernel<<<dim3(out_size), dim3(TPB), 0, stream>>>(
        state_batch, var_params, head_w, head_b, out);
}